// Round 1
// baseline (3186.352 us; speedup 1.0000x reference)
//
#include <hip/hip_runtime.h>
#include <math.h>

#define NB 8
#define NG 2048
#define NK 32
#define NO 128
#define NM 64
#define NC 131
#define NGRP (NB*NG)          // 16384 (b,g) groups
#define NWG 2048              // persistent workgroups for tile passes
#define GPW 8                 // groups per workgroup
#define NPT (NB*NG*NK)        // 524288 positions

// workspace layout (float offsets)
#define OFF_STD_PART 0                                   // 256*2
#define OFF_STD      512                                 // 1 (std scalar)
#define OFF_BN1_PART 1024                                // NWG*128*2
#define OFF_BN1_STAT (OFF_BN1_PART + (size_t)NWG*128*2)  // 128*2
#define OFF_BND_PART (OFF_BN1_STAT + 256)                // NWG*64*2
#define OFF_BND_STAT (OFF_BND_PART + (size_t)NWG*64*2)   // 64*2
#define OFF_BNU_PART (OFF_BND_STAT + 128)                // NWG*128*2
#define OFF_BNU_STAT (OFF_BNU_PART + (size_t)NWG*128*2)  // 128*2

// ---------------- std of rel0 (ddof=1) ----------------
__global__ __launch_bounds__(256) void k_std_part(const float* __restrict__ knn_xyz,
                                                  const float* __restrict__ lc_xyz,
                                                  float* __restrict__ part) {
  int t = threadIdx.x, blk = blockIdx.x;
  int gsz = gridDim.x * blockDim.x;
  float s = 0.f, s2 = 0.f;
  for (int i = blk*256 + t; i < NPT*3; i += gsz) {
    int d = i % 3;
    int pk = i / 3;
    int bg = pk / NK;
    float r = knn_xyz[i] - lc_xyz[bg*3 + d];
    s += r; s2 += r*r;
  }
  __shared__ float ls[256], ls2[256];
  ls[t] = s; ls2[t] = s2; __syncthreads();
  for (int off = 128; off >= 1; off >>= 1) {
    if (t < off) { ls[t] += ls[t+off]; ls2[t] += ls2[t+off]; }
    __syncthreads();
  }
  if (t == 0) { part[blk*2] = ls[0]; part[blk*2+1] = ls2[0]; }
}

__global__ __launch_bounds__(256) void k_std_fin(const float* __restrict__ part,
                                                 float* __restrict__ wsc) {
  int t = threadIdx.x;
  __shared__ float ls[256], ls2[256];
  ls[t] = part[t*2]; ls2[t] = part[t*2+1]; __syncthreads();
  for (int off = 128; off >= 1; off >>= 1) {
    if (t < off) { ls[t] += ls[t+off]; ls2[t] += ls2[t+off]; }
    __syncthreads();
  }
  if (t == 0) {
    double S = ls[0], S2 = ls2[0];
    double n = (double)NPT * 3.0;
    double var = (S2 - S*S/n) / (n - 1.0);
    wsc[0] = (float)(sqrt(var) + 1e-5);
  }
}

// ---------------- z1 = W1 * expanded, write to out, partial BN1 stats ----------------
__global__ __launch_bounds__(256) void k_z1(const float* __restrict__ knn_feat,
                                            const float* __restrict__ lc_feat,
                                            const float* __restrict__ w1,
                                            float* __restrict__ out,
                                            float* __restrict__ part) {
  __shared__ float eT[NK*132];     // [k][c], pad 132
  __shared__ float wbuf[64*132];   // 64 rows of w1, pad 132
  int t = threadIdx.x, blk = blockIdx.x;
  int k = t & 31, og = t >> 5, oi = og*8;
  float sacc[16], sacc2[16];
#pragma unroll
  for (int j = 0; j < 16; ++j) { sacc[j] = 0.f; sacc2[j] = 0.f; }
  for (int ph = 0; ph < 2; ++ph) {
    __syncthreads();
    const float* w1p = w1 + (size_t)ph*64*NC;
    for (int i = t; i < 64*NC; i += 256) { int r = i/NC, c = i - r*NC; wbuf[r*132+c] = w1p[i]; }
    for (int gi = 0; gi < GPW; ++gi) {
      int bg = blk*GPW + gi;
      __syncthreads();
      const float* kf = knn_feat + (size_t)bg*NK*67;
      for (int i = t; i < NK*67; i += 256) { int kk = i/67, c = i - kk*67; eT[kk*132+c] = kf[i]; }
      const float* lf = lc_feat + (size_t)bg*64;
      for (int i = t; i < NK*64; i += 256) { int kk = i >> 6, c = i & 63; eT[kk*132+67+c] = lf[c]; }
      __syncthreads();
      float acc[8];
#pragma unroll
      for (int j = 0; j < 8; ++j) acc[j] = 0.f;
      const float* ep = &eT[k*132];
      for (int c4 = 0; c4 < 128; c4 += 4) {
        float4 ev = *(const float4*)(ep + c4);
#pragma unroll
        for (int j = 0; j < 8; ++j) {
          float4 wv = *(const float4*)&wbuf[(oi+j)*132 + c4];
          acc[j] += wv.x*ev.x + wv.y*ev.y + wv.z*ev.z + wv.w*ev.w;
        }
      }
      float e0 = ep[128], e1 = ep[129], e2 = ep[130];
#pragma unroll
      for (int j = 0; j < 8; ++j) {
        const float* wr = &wbuf[(oi+j)*132];
        acc[j] += wr[128]*e0 + wr[129]*e1 + wr[130]*e2;
      }
      int b = bg >> 11, g = bg & (NG-1);
#pragma unroll
      for (int j = 0; j < 8; ++j) {
        int o = ph*64 + oi + j;
        out[(((size_t)b*NO + o)*NG + g)*NK + k] = acc[j];
        sacc[ph*8+j] += acc[j];
        sacc2[ph*8+j] += acc[j]*acc[j];
      }
    }
  }
#pragma unroll
  for (int si = 0; si < 16; ++si) {
    float v = sacc[si], v2 = sacc2[si];
    for (int m = 16; m >= 1; m >>= 1) { v += __shfl_xor(v, m); v2 += __shfl_xor(v2, m); }
    if (k == 0) {
      int o = (si >> 3)*64 + oi + (si & 7);
      part[((size_t)blk*NO + o)*2 + 0] = v;
      part[((size_t)blk*NO + o)*2 + 1] = v2;
    }
  }
}

// ---------------- generic BN finalize: scale/shift from partials ----------------
__global__ __launch_bounds__(256) void k_fin_bn(const float* __restrict__ part, int C, float n,
                                                const float* __restrict__ gamma,
                                                const float* __restrict__ beta,
                                                float* __restrict__ stat) {
  int o = blockIdx.x, t = threadIdx.x;
  float s = 0.f, s2 = 0.f;
  for (int w = t; w < NWG; w += 256) {
    s  += part[((size_t)w*C + o)*2 + 0];
    s2 += part[((size_t)w*C + o)*2 + 1];
  }
  __shared__ float ls[256], ls2[256];
  ls[t] = s; ls2[t] = s2; __syncthreads();
  for (int off = 128; off >= 1; off >>= 1) {
    if (t < off) { ls[t] += ls[t+off]; ls2[t] += ls2[t+off]; }
    __syncthreads();
  }
  if (t == 0) {
    float mean = ls[0] / n;
    float var  = ls2[0] / n - mean*mean;
    float sc = gamma[o] * rsqrtf(var + 1e-5f);
    stat[o*2]   = sc;
    stat[o*2+1] = beta[o] - mean*sc;
  }
}

// ---------------- apply BN1+relu+gauss weight in place, partial h_pre0 stats ----------------
__global__ __launch_bounds__(256) void k_x1(const float* __restrict__ knn_xyz,
                                            const float* __restrict__ lc_xyz,
                                            const float* __restrict__ wd,
                                            const float* __restrict__ bd,
                                            float* __restrict__ out,
                                            const float* __restrict__ wsc,
                                            const float* __restrict__ bn1_stat,
                                            float* __restrict__ part) {
  __shared__ float xT[NK*132];
  __shared__ float wbuf[NM*132];
  __shared__ float s_sc[NO], s_sh[NO], s_bd[NM], wgt[NK];
  int t = threadIdx.x, blk = blockIdx.x;
  int k = t & 31, og = t >> 5, mi = og*8;
  for (int i = t; i < NM*NO; i += 256) { int r = i >> 7, c = i & 127; wbuf[r*132+c] = wd[i]; }
  for (int i = t; i < NO; i += 256) { s_sc[i] = bn1_stat[i*2]; s_sh[i] = bn1_stat[i*2+1]; }
  if (t < NM) s_bd[t] = bd[t];
  float inv_std = 1.0f / wsc[0];
  float sacc[8], sacc2[8];
#pragma unroll
  for (int j = 0; j < 8; ++j) { sacc[j] = 0.f; sacc2[j] = 0.f; }
  for (int gi = 0; gi < GPW; ++gi) {
    int bg = blk*GPW + gi;
    __syncthreads();
    if (t < NK) {
      const float* kx = knn_xyz + ((size_t)bg*NK + t)*3;
      const float* lc = lc_xyz + (size_t)bg*3;
      float d2 = 0.f;
#pragma unroll
      for (int d = 0; d < 3; ++d) { float r = (kx[d]-lc[d])*inv_std - lc[d]; d2 += r*r; }
      wgt[t] = expf(-sqrtf(d2)*0.5f);
    }
    __syncthreads();
    int b = bg >> 11, g = bg & (NG-1);
    for (int i = t; i < NO*NK; i += 256) {
      int o = i >> 5, kk = i & 31;
      size_t gidx = (((size_t)b*NO + o)*NG + g)*NK + kk;
      float z = out[gidx];
      float v = fmaxf(z*s_sc[o] + s_sh[o], 0.f) * wgt[kk];
      out[gidx] = v;
      xT[kk*132+o] = v;
    }
    __syncthreads();
    float acc[8];
#pragma unroll
    for (int j = 0; j < 8; ++j) acc[j] = s_bd[mi+j];
    const float* xp = &xT[k*132];
    for (int c4 = 0; c4 < 128; c4 += 4) {
      float4 xv = *(const float4*)(xp + c4);
#pragma unroll
      for (int j = 0; j < 8; ++j) {
        float4 wv = *(const float4*)&wbuf[(mi+j)*132 + c4];
        acc[j] += wv.x*xv.x + wv.y*xv.y + wv.z*xv.z + wv.w*xv.w;
      }
    }
#pragma unroll
    for (int j = 0; j < 8; ++j) { sacc[j] += acc[j]; sacc2[j] += acc[j]*acc[j]; }
  }
#pragma unroll
  for (int j = 0; j < 8; ++j) {
    float v = sacc[j], v2 = sacc2[j];
    for (int m = 16; m >= 1; m >>= 1) { v += __shfl_xor(v, m); v2 += __shfl_xor(v2, m); }
    if (k == 0) {
      part[((size_t)blk*NM + mi + j)*2 + 0] = v;
      part[((size_t)blk*NM + mi + j)*2 + 1] = v2;
    }
  }
}

// ---------------- pass B: recompute h, partial u_pre stats ----------------
__global__ __launch_bounds__(256) void k_bstat(const float* __restrict__ out,
                                               const float* __restrict__ wd,
                                               const float* __restrict__ bd,
                                               const float* __restrict__ wu,
                                               const float* __restrict__ bu,
                                               const float* __restrict__ bnd_stat,
                                               float* __restrict__ part) {
  __shared__ float xT[NK*132];
  __shared__ float hT[NK*68];
  __shared__ float wbuf[NO*68];   // max(64*132, 128*68) = 8704 floats
  __shared__ float s_sc[NM], s_sh[NM], s_bd[NM], s_bu[NO];
  int t = threadIdx.x, blk = blockIdx.x;
  int k = t & 31, og = t >> 5;
  if (t < NM) { s_sc[t] = bnd_stat[t*2]; s_sh[t] = bnd_stat[t*2+1]; s_bd[t] = bd[t]; }
  for (int i = t; i < NO; i += 256) s_bu[i] = bu[i];
  float sacc[16], sacc2[16];
#pragma unroll
  for (int j = 0; j < 16; ++j) { sacc[j] = 0.f; sacc2[j] = 0.f; }
  for (int gi = 0; gi < GPW; ++gi) {
    int bg = blk*GPW + gi;
    int b = bg >> 11, g = bg & (NG-1);
    __syncthreads();
    for (int i = t; i < NO*NK; i += 256) {
      int o = i >> 5, kk = i & 31;
      xT[kk*132+o] = out[(((size_t)b*NO + o)*NG + g)*NK + kk];
    }
    for (int i = t; i < NM*NO; i += 256) { int r = i >> 7, c = i & 127; wbuf[r*132+c] = wd[i]; }
    __syncthreads();
    {
      int mi = og*8;
      float acc[8];
#pragma unroll
      for (int j = 0; j < 8; ++j) acc[j] = s_bd[mi+j];
      const float* xp = &xT[k*132];
      for (int c4 = 0; c4 < 128; c4 += 4) {
        float4 xv = *(const float4*)(xp + c4);
#pragma unroll
        for (int j = 0; j < 8; ++j) {
          float4 wv = *(const float4*)&wbuf[(mi+j)*132 + c4];
          acc[j] += wv.x*xv.x + wv.y*xv.y + wv.z*xv.z + wv.w*xv.w;
        }
      }
#pragma unroll
      for (int j = 0; j < 8; ++j)
        hT[k*68 + mi + j] = fmaxf(acc[j]*s_sc[mi+j] + s_sh[mi+j], 0.f);
    }
    __syncthreads();
    for (int i = t; i < NO*NM; i += 256) { int r = i >> 6, c = i & 63; wbuf[r*68+c] = wu[i]; }
    __syncthreads();
    {
      int oi = og*16;
      float acc[16];
#pragma unroll
      for (int j = 0; j < 16; ++j) acc[j] = s_bu[oi+j];
      const float* hp = &hT[k*68];
      for (int c4 = 0; c4 < 64; c4 += 4) {
        float4 hv = *(const float4*)(hp + c4);
#pragma unroll
        for (int j = 0; j < 16; ++j) {
          float4 wv = *(const float4*)&wbuf[(oi+j)*68 + c4];
          acc[j] += wv.x*hv.x + wv.y*hv.y + wv.z*hv.z + wv.w*hv.w;
        }
      }
#pragma unroll
      for (int j = 0; j < 16; ++j) { sacc[j] += acc[j]; sacc2[j] += acc[j]*acc[j]; }
    }
  }
  int oi = og*16;
#pragma unroll
  for (int j = 0; j < 16; ++j) {
    float v = sacc[j], v2 = sacc2[j];
    for (int m = 16; m >= 1; m >>= 1) { v += __shfl_xor(v, m); v2 += __shfl_xor(v2, m); }
    if (k == 0) {
      part[((size_t)blk*NO + oi + j)*2 + 0] = v;
      part[((size_t)blk*NO + oi + j)*2 + 1] = v2;
    }
  }
}

// ---------------- pass C: full block, residual, optional next-block h_pre stats ----------------
__global__ __launch_bounds__(256) void k_bfin(float* __restrict__ out,
                                              const float* __restrict__ wd,
                                              const float* __restrict__ bd,
                                              const float* __restrict__ wu,
                                              const float* __restrict__ bu,
                                              const float* __restrict__ bnd_stat,
                                              const float* __restrict__ bnu_stat,
                                              const float* __restrict__ wd_next,
                                              const float* __restrict__ bd_next,
                                              float* __restrict__ part,
                                              int do_next) {
  __shared__ float xT[NK*132];
  __shared__ float hT[NK*68];
  __shared__ float wbuf[NO*68];
  __shared__ float s_scd[NM], s_shd[NM], s_bd[NM];
  __shared__ float s_bu[NO], s_scu[NO], s_shu[NO], s_bdn[NM];
  int t = threadIdx.x, blk = blockIdx.x;
  int k = t & 31, og = t >> 5;
  if (t < NM) { s_scd[t] = bnd_stat[t*2]; s_shd[t] = bnd_stat[t*2+1]; s_bd[t] = bd[t];
                s_bdn[t] = do_next ? bd_next[t] : 0.f; }
  for (int i = t; i < NO; i += 256) { s_bu[i] = bu[i]; s_scu[i] = bnu_stat[i*2]; s_shu[i] = bnu_stat[i*2+1]; }
  float sacc[8], sacc2[8];
#pragma unroll
  for (int j = 0; j < 8; ++j) { sacc[j] = 0.f; sacc2[j] = 0.f; }
  for (int gi = 0; gi < GPW; ++gi) {
    int bg = blk*GPW + gi;
    int b = bg >> 11, g = bg & (NG-1);
    __syncthreads();
    for (int i = t; i < NO*NK; i += 256) {
      int o = i >> 5, kk = i & 31;
      xT[kk*132+o] = out[(((size_t)b*NO + o)*NG + g)*NK + kk];
    }
    for (int i = t; i < NM*NO; i += 256) { int r = i >> 7, c = i & 127; wbuf[r*132+c] = wd[i]; }
    __syncthreads();
    {
      int mi = og*8;
      float acc[8];
#pragma unroll
      for (int j = 0; j < 8; ++j) acc[j] = s_bd[mi+j];
      const float* xp = &xT[k*132];
      for (int c4 = 0; c4 < 128; c4 += 4) {
        float4 xv = *(const float4*)(xp + c4);
#pragma unroll
        for (int j = 0; j < 8; ++j) {
          float4 wv = *(const float4*)&wbuf[(mi+j)*132 + c4];
          acc[j] += wv.x*xv.x + wv.y*xv.y + wv.z*xv.z + wv.w*xv.w;
        }
      }
#pragma unroll
      for (int j = 0; j < 8; ++j)
        hT[k*68 + mi + j] = fmaxf(acc[j]*s_scd[mi+j] + s_shd[mi+j], 0.f);
    }
    __syncthreads();
    for (int i = t; i < NO*NM; i += 256) { int r = i >> 6, c = i & 63; wbuf[r*68+c] = wu[i]; }
    __syncthreads();
    {
      int oi = og*16;
      float acc[16];
#pragma unroll
      for (int j = 0; j < 16; ++j) acc[j] = s_bu[oi+j];
      const float* hp = &hT[k*68];
      for (int c4 = 0; c4 < 64; c4 += 4) {
        float4 hv = *(const float4*)(hp + c4);
#pragma unroll
        for (int j = 0; j < 16; ++j) {
          float4 wv = *(const float4*)&wbuf[(oi+j)*68 + c4];
          acc[j] += wv.x*hv.x + wv.y*hv.y + wv.z*hv.z + wv.w*hv.w;
        }
      }
#pragma unroll
      for (int j = 0; j < 16; ++j) {
        int o = oi + j;
        float u = acc[j]*s_scu[o] + s_shu[o];
        float xn = fmaxf(u + xT[k*132+o], 0.f);
        out[(((size_t)b*NO + o)*NG + g)*NK + k] = xn;
        xT[k*132+o] = xn;
      }
    }
    if (do_next) {
      __syncthreads();
      for (int i = t; i < NM*NO; i += 256) { int r = i >> 7, c = i & 127; wbuf[r*132+c] = wd_next[i]; }
      __syncthreads();
      int mi = og*8;
      float acc[8];
#pragma unroll
      for (int j = 0; j < 8; ++j) acc[j] = s_bdn[mi+j];
      const float* xp = &xT[k*132];
      for (int c4 = 0; c4 < 128; c4 += 4) {
        float4 xv = *(const float4*)(xp + c4);
#pragma unroll
        for (int j = 0; j < 8; ++j) {
          float4 wv = *(const float4*)&wbuf[(mi+j)*132 + c4];
          acc[j] += wv.x*xv.x + wv.y*xv.y + wv.z*xv.z + wv.w*xv.w;
        }
      }
#pragma unroll
      for (int j = 0; j < 8; ++j) { sacc[j] += acc[j]; sacc2[j] += acc[j]*acc[j]; }
    }
  }
  if (do_next) {
    int mi = og*8;
#pragma unroll
    for (int j = 0; j < 8; ++j) {
      float v = sacc[j], v2 = sacc2[j];
      for (int m = 16; m >= 1; m >>= 1) { v += __shfl_xor(v, m); v2 += __shfl_xor(v2, m); }
      if (k == 0) {
        part[((size_t)blk*NM + mi + j)*2 + 0] = v;
        part[((size_t)blk*NM + mi + j)*2 + 1] = v2;
      }
    }
  }
}

extern "C" void kernel_launch(void* const* d_in, const int* in_sizes, int n_in,
                              void* d_out, int out_size, void* d_ws, size_t ws_size,
                              hipStream_t stream) {
  const float* lc_xyz   = (const float*)d_in[0];
  const float* lc_feat  = (const float*)d_in[1];
  const float* knn_xyz  = (const float*)d_in[2];
  const float* knn_feat = (const float*)d_in[3];
  const float* w1       = (const float*)d_in[4];
  const float* bn1_g    = (const float*)d_in[5];
  const float* bn1_b    = (const float*)d_in[6];
  const float* wd       = (const float*)d_in[7];
  const float* bd       = (const float*)d_in[8];
  const float* dn_g     = (const float*)d_in[9];
  const float* dn_b     = (const float*)d_in[10];
  const float* wu       = (const float*)d_in[11];
  const float* bu       = (const float*)d_in[12];
  const float* up_g     = (const float*)d_in[13];
  const float* up_b     = (const float*)d_in[14];
  float* out = (float*)d_out;
  float* ws  = (float*)d_ws;
  const float n = (float)NPT;

  k_std_part<<<256, 256, 0, stream>>>(knn_xyz, lc_xyz, ws + OFF_STD_PART);
  k_std_fin<<<1, 256, 0, stream>>>(ws + OFF_STD_PART, ws + OFF_STD);

  k_z1<<<NWG, 256, 0, stream>>>(knn_feat, lc_feat, w1, out, ws + OFF_BN1_PART);
  k_fin_bn<<<128, 256, 0, stream>>>(ws + OFF_BN1_PART, 128, n, bn1_g, bn1_b, ws + OFF_BN1_STAT);

  k_x1<<<NWG, 256, 0, stream>>>(knn_xyz, lc_xyz, wd, bd, out, ws + OFF_STD,
                                ws + OFF_BN1_STAT, ws + OFF_BND_PART);
  k_fin_bn<<<64, 256, 0, stream>>>(ws + OFF_BND_PART, 64, n, dn_g, dn_b, ws + OFF_BND_STAT);

  k_bstat<<<NWG, 256, 0, stream>>>(out, wd, bd, wu, bu, ws + OFF_BND_STAT, ws + OFF_BNU_PART);
  k_fin_bn<<<128, 256, 0, stream>>>(ws + OFF_BNU_PART, 128, n, up_g, up_b, ws + OFF_BNU_STAT);

  k_bfin<<<NWG, 256, 0, stream>>>(out, wd, bd, wu, bu, ws + OFF_BND_STAT, ws + OFF_BNU_STAT,
                                  wd + 64*128, bd + 64, ws + OFF_BND_PART, 1);
  k_fin_bn<<<64, 256, 0, stream>>>(ws + OFF_BND_PART, 64, n, dn_g + 64, dn_b + 64, ws + OFF_BND_STAT);

  k_bstat<<<NWG, 256, 0, stream>>>(out, wd + 64*128, bd + 64, wu + 128*64, bu + 128,
                                   ws + OFF_BND_STAT, ws + OFF_BNU_PART);
  k_fin_bn<<<128, 256, 0, stream>>>(ws + OFF_BNU_PART, 128, n, up_g + 128, up_b + 128, ws + OFF_BNU_STAT);

  k_bfin<<<NWG, 256, 0, stream>>>(out, wd + 64*128, bd + 64, wu + 128*64, bu + 128,
                                  ws + OFF_BND_STAT, ws + OFF_BNU_STAT,
                                  nullptr, nullptr, nullptr, 0);
}

// Round 3
// 1347.973 us; speedup vs baseline: 2.3638x; 2.3638x over previous
//
#include <hip/hip_runtime.h>
#include <math.h>

#define NB 8
#define NG 2048
#define NK 32
#define NO 128
#define NM 64
#define NC 131
#define NPT (NB*NG*NK)      // 524288 positions
#define NWGT 2048           // blocks for tile passes
#define TPW 4               // tiles (of 64 positions) per workgroup
#define NROWS2 (NWGT*2)
#define NROWS4 (NWGT*4)

// LDS row strides (bf16 elements) -- all 16B-aligned, bank-uniform.
// XOR swizzle works on octet index (c>>3) ^ ((pos>>2)&7): octet count MUST be a
// multiple of 8 so every 8-octet group is closed under the XOR (round-2 bug:
// ES=168 = 21 octets overflowed rows for octets 16..19).
#define XS 136              // xT (K=128 -> 16 octets, closed; +1 octet pad)
#define ES 192              // eT (K padded 131 -> 24 octets, 3 closed groups)
#define HS 72               // hT (K=64 -> 8 octets, closed; +1 octet pad)

// workspace layout (float offsets)
#define OFF_STD_PART 0
#define OFF_STD      512
#define OFF_STATA    1024   // 256
#define OFF_STATB    1536   // 128
#define OFF_STATC    2048   // 256
#define OFF_PART     4096   // 1,048,576 floats max

typedef __attribute__((ext_vector_type(8))) short short8v;
typedef __attribute__((ext_vector_type(4))) float f32x4;

#define MFMA(a,b,c) __builtin_amdgcn_mfma_f32_16x16x32_bf16(a,b,c,0,0,0)

__device__ inline unsigned short f2bf(float f) {
  unsigned u = __builtin_bit_cast(unsigned, f);
  unsigned r = u + 0x7fffu + ((u >> 16) & 1u);
  return (unsigned short)(r >> 16);
}

// ---------------- std of rel0 (ddof=1) ----------------
__global__ __launch_bounds__(256) void k_std_part(const float* __restrict__ knn_xyz,
                                                  const float* __restrict__ lc_xyz,
                                                  float* __restrict__ part) {
  int t = threadIdx.x, blk = blockIdx.x;
  int gsz = gridDim.x * blockDim.x;
  float s = 0.f, s2 = 0.f;
  for (int i = blk*256 + t; i < NPT*3; i += gsz) {
    int d = i % 3;
    int pk = i / 3;
    int bg = pk / NK;
    float r = knn_xyz[i] - lc_xyz[bg*3 + d];
    s += r; s2 += r*r;
  }
  __shared__ float ls[256], ls2[256];
  ls[t] = s; ls2[t] = s2; __syncthreads();
  for (int off = 128; off >= 1; off >>= 1) {
    if (t < off) { ls[t] += ls[t+off]; ls2[t] += ls2[t+off]; }
    __syncthreads();
  }
  if (t == 0) { part[blk*2] = ls[0]; part[blk*2+1] = ls2[0]; }
}

__global__ __launch_bounds__(256) void k_std_fin(const float* __restrict__ part,
                                                 float* __restrict__ wsc) {
  int t = threadIdx.x;
  __shared__ float ls[256], ls2[256];
  ls[t] = part[t*2]; ls2[t] = part[t*2+1]; __syncthreads();
  for (int off = 128; off >= 1; off >>= 1) {
    if (t < off) { ls[t] += ls[t+off]; ls2[t] += ls2[t+off]; }
    __syncthreads();
  }
  if (t == 0) {
    double S = ls[0], S2 = ls2[0];
    double n = (double)NPT * 3.0;
    double var = (S2 - S*S/n) / (n - 1.0);
    wsc[0] = (float)(sqrt(var) + 1e-5);
  }
}

// ---------------- BN finalize ----------------
__global__ __launch_bounds__(256) void k_fin_bn(const float* __restrict__ part, int C, int nrows,
                                                const float* __restrict__ gamma,
                                                const float* __restrict__ beta,
                                                float* __restrict__ stat) {
  int o = blockIdx.x, t = threadIdx.x;
  float s = 0.f, s2 = 0.f;
  for (int r = t; r < nrows; r += 256) {
    s  += part[((size_t)r*C + o)*2 + 0];
    s2 += part[((size_t)r*C + o)*2 + 1];
  }
  __shared__ float ls[256], ls2[256];
  ls[t] = s; ls2[t] = s2; __syncthreads();
  for (int off = 128; off >= 1; off >>= 1) {
    if (t < off) { ls[t] += ls[t+off]; ls2[t] += ls2[t+off]; }
    __syncthreads();
  }
  if (t == 0) {
    float n = (float)NPT;
    float mean = ls[0] / n;
    float var  = ls2[0] / n - mean*mean;
    float sc = gamma[o] * rsqrtf(var + 1e-5f);
    stat[o*2]   = sc;
    stat[o*2+1] = beta[o] - mean*sc;
  }
}

// ---------------- z1 = expanded @ W1^T (MFMA), write f32, BN1 partials ----------------
__global__ __launch_bounds__(256) void k_z1(const float* __restrict__ knn_feat,
                                            const float* __restrict__ lc_feat,
                                            const float* __restrict__ w1,
                                            float* __restrict__ out,
                                            float* __restrict__ part) {
  __shared__ __align__(16) unsigned short eT[64*ES];  // 24576 B
  __shared__ __align__(16) float zB[128*68];          // 34816 B
  int t = threadIdx.x, blk = blockIdx.x;
  int lane = t & 63, w = t >> 6;
  int p = lane & 15, q = lane >> 4;
  int mpair = w & 1, nhalf = w >> 1;

  // resident W1 fragments: [ntile][kstep], K padded 131 -> 160
  short8v wf[4][5];
#pragma unroll
  for (int nt = 0; nt < 4; ++nt)
#pragma unroll
    for (int ks = 0; ks < 5; ++ks) {
      int row = nhalf*64 + nt*16 + p;
      int kb = ks*32 + q*8;
      short8v f;
#pragma unroll
      for (int j = 0; j < 8; ++j) {
        int k = kb + j;
        f[j] = (short)((k < NC) ? f2bf(w1[row*NC + k]) : 0);
      }
      wf[nt][ks] = f;
    }

  float ss[4], ss2[4];
#pragma unroll
  for (int nt = 0; nt < 4; ++nt) { ss[nt] = 0.f; ss2[nt] = 0.f; }

  for (int gi = 0; gi < TPW; ++gi) {
    int tile = blk*TPW + gi;
    int bg0 = tile*2;
    int b = bg0 >> 11, g0 = bg0 & (NG-1);
    __syncthreads();
    // stage expanded -> eT (bf16, swizzled)
    const float* kf = knn_feat + (size_t)bg0*NK*67;
    for (int i = t; i < 64*67; i += 256) {
      int pos = i/67, c = i - pos*67;
      eT[pos*ES + ((((c>>3) ^ ((pos>>2)&7))<<3) | (c&7))] = f2bf(kf[i]);
    }
    const float* lf = lc_feat + (size_t)bg0*64;
    for (int i = t; i < 64*64; i += 256) {
      int pos = i >> 6, c = i & 63;
      int ch = 67 + c;
      eT[pos*ES + ((((ch>>3) ^ ((pos>>2)&7))<<3) | (ch&7))] = f2bf(lf[(pos>>5)*64 + c]);
    }
    for (int i = t; i < 64*32; i += 256) {
      int pos = i >> 5, c = 131 + (i & 31);
      if (c < 160)
        eT[pos*ES + ((((c>>3) ^ ((pos>>2)&7))<<3) | (c&7))] = 0;
    }
    __syncthreads();

    f32x4 acc[2][4];
#pragma unroll
    for (int mt = 0; mt < 2; ++mt)
#pragma unroll
      for (int nt = 0; nt < 4; ++nt) acc[mt][nt] = (f32x4){0.f,0.f,0.f,0.f};
#pragma unroll
    for (int ks = 0; ks < 5; ++ks) {
#pragma unroll
      for (int mt = 0; mt < 2; ++mt) {
        int pos = mpair*32 + mt*16 + p;
        int kb8 = ks*4 + q;
        short8v a = *(const short8v*)&eT[pos*ES + ((kb8 ^ ((pos>>2)&7))<<3)];
#pragma unroll
        for (int nt = 0; nt < 4; ++nt) acc[mt][nt] = MFMA(a, wf[nt][ks], acc[mt][nt]);
      }
    }
    // stats
#pragma unroll
    for (int mt = 0; mt < 2; ++mt)
#pragma unroll
      for (int nt = 0; nt < 4; ++nt)
#pragma unroll
        for (int r = 0; r < 4; ++r) { float v = acc[mt][nt][r]; ss[nt] += v; ss2[nt] += v*v; }
    // bounce to zB (f32) and write out coalesced
#pragma unroll
    for (int mt = 0; mt < 2; ++mt)
#pragma unroll
      for (int nt = 0; nt < 4; ++nt) {
        int ch = nhalf*64 + nt*16 + p;
        int posb = mpair*32 + mt*16 + q*4;
        *(f32x4*)&zB[ch*68 + posb] = acc[mt][nt];
      }
    __syncthreads();
    for (int i = t; i < 128*16; i += 256) {
      int ch = i >> 4, p4 = (i & 15) * 4;
      f32x4 v = *(const f32x4*)&zB[ch*68 + p4];
      *(f32x4*)&out[(((size_t)b*NO + ch)*NG + g0)*NK + p4] = v;
    }
  }
#pragma unroll
  for (int nt = 0; nt < 4; ++nt) {
    float v = ss[nt], v2 = ss2[nt];
    v += __shfl_xor(v, 16); v += __shfl_xor(v, 32);
    v2 += __shfl_xor(v2, 16); v2 += __shfl_xor(v2, 32);
    if (q == 0) {
      int ch = nhalf*64 + nt*16 + p;
      size_t row = (size_t)blk*2 + mpair;
      part[(row*NO + ch)*2 + 0] = v;
      part[(row*NO + ch)*2 + 1] = v2;
    }
  }
}

// ---------------- x1 = relu(bn1(z1))*wgt in place + down0 h_pre partials ----------------
__global__ __launch_bounds__(256) void k_x1(const float* __restrict__ knn_xyz,
                                            const float* __restrict__ lc_xyz,
                                            const float* __restrict__ wd,
                                            const float* __restrict__ bd,
                                            float* __restrict__ out,
                                            const float* __restrict__ wsc,
                                            const float* __restrict__ bn1_stat,
                                            float* __restrict__ part) {
  __shared__ __align__(16) unsigned short xT[64*XS];
  __shared__ float s_sc[NO], s_sh[NO], s_bd[NM], s_wgt[64];
  int t = threadIdx.x, blk = blockIdx.x;
  int lane = t & 63, w = t >> 6;
  int p = lane & 15, q = lane >> 4;

  short8v wf[4][4];
#pragma unroll
  for (int nt = 0; nt < 4; ++nt)
#pragma unroll
    for (int ks = 0; ks < 4; ++ks) {
      int row = nt*16 + p;
      int kb = ks*32 + q*8;
      short8v f;
#pragma unroll
      for (int j = 0; j < 8; ++j) f[j] = (short)f2bf(wd[row*NO + kb + j]);
      wf[nt][ks] = f;
    }
  for (int i = t; i < NO; i += 256) { s_sc[i] = bn1_stat[i*2]; s_sh[i] = bn1_stat[i*2+1]; }
  if (t < NM) s_bd[t] = bd[t];
  float inv_std = 1.0f / wsc[0];

  float ss[4], ss2[4];
#pragma unroll
  for (int nt = 0; nt < 4; ++nt) { ss[nt] = 0.f; ss2[nt] = 0.f; }

  for (int gi = 0; gi < TPW; ++gi) {
    int tile = blk*TPW + gi;
    int bg0 = tile*2;
    int b = bg0 >> 11, g0 = bg0 & (NG-1);
    __syncthreads();
    if (t < 64) {
      const float* kx = knn_xyz + ((size_t)bg0*NK + t)*3;
      const float* lc = lc_xyz + ((size_t)bg0 + (t>>5))*3;
      float d2 = 0.f;
#pragma unroll
      for (int d = 0; d < 3; ++d) { float r = (kx[d]-lc[d])*inv_std - lc[d]; d2 += r*r; }
      s_wgt[t] = expf(-sqrtf(d2)*0.5f);
    }
    __syncthreads();
#pragma unroll
    for (int it = 0; it < 8; ++it) {
      int i = t + it*256;
      int ch = i >> 4, p4 = (i & 15)*4;
      size_t gaddr = (((size_t)b*NO + ch)*NG + g0)*NK + p4;
      f32x4 z = *(const f32x4*)&out[gaddr];
      float sc = s_sc[ch], sh = s_sh[ch];
      int swz = ((((ch>>3) ^ ((p4>>2)&7))<<3) | (ch&7));
      f32x4 x;
#pragma unroll
      for (int r = 0; r < 4; ++r) {
        float v = fmaxf(z[r]*sc + sh, 0.f) * s_wgt[p4+r];
        x[r] = v;
        xT[(p4+r)*XS + swz] = f2bf(v);
      }
      *(f32x4*)&out[gaddr] = x;
    }
    __syncthreads();
    f32x4 acc[4];
#pragma unroll
    for (int nt = 0; nt < 4; ++nt) acc[nt] = (f32x4){0.f,0.f,0.f,0.f};
#pragma unroll
    for (int ks = 0; ks < 4; ++ks) {
      int pos = w*16 + p;
      int kb8 = ks*4 + q;
      short8v a = *(const short8v*)&xT[pos*XS + ((kb8 ^ ((pos>>2)&7))<<3)];
#pragma unroll
      for (int nt = 0; nt < 4; ++nt) acc[nt] = MFMA(a, wf[nt][ks], acc[nt]);
    }
#pragma unroll
    for (int nt = 0; nt < 4; ++nt) {
      float bdv = s_bd[nt*16 + p];
#pragma unroll
      for (int r = 0; r < 4; ++r) { float v = acc[nt][r] + bdv; ss[nt] += v; ss2[nt] += v*v; }
    }
  }
#pragma unroll
  for (int nt = 0; nt < 4; ++nt) {
    float v = ss[nt], v2 = ss2[nt];
    v += __shfl_xor(v, 16); v += __shfl_xor(v, 32);
    v2 += __shfl_xor(v2, 16); v2 += __shfl_xor(v2, 32);
    if (q == 0) {
      int ch = nt*16 + p;
      size_t row = (size_t)blk*4 + w;
      part[(row*NM + ch)*2 + 0] = v;
      part[(row*NM + ch)*2 + 1] = v2;
    }
  }
}

// ---------------- pass B: down+up recompute, u_pre partials ----------------
__global__ __launch_bounds__(256) void k_bstat(const float* __restrict__ out,
                                               const float* __restrict__ wd,
                                               const float* __restrict__ bd,
                                               const float* __restrict__ wu,
                                               const float* __restrict__ bu,
                                               const float* __restrict__ bnd_stat,
                                               float* __restrict__ part) {
  __shared__ __align__(16) unsigned short xT[64*XS];
  __shared__ __align__(16) unsigned short hT[64*HS];
  __shared__ float s_c1[NM], s_c0[NM], s_bu[NO];
  int t = threadIdx.x, blk = blockIdx.x;
  int lane = t & 63, w = t >> 6;
  int p = lane & 15, q = lane >> 4;
  int mpair = w & 1, nhalf = w >> 1;

  short8v wfd[4][4];
#pragma unroll
  for (int nt = 0; nt < 4; ++nt)
#pragma unroll
    for (int ks = 0; ks < 4; ++ks) {
      int row = nt*16 + p;
      int kb = ks*32 + q*8;
      short8v f;
#pragma unroll
      for (int j = 0; j < 8; ++j) f[j] = (short)f2bf(wd[row*NO + kb + j]);
      wfd[nt][ks] = f;
    }
  short8v wfu[4][2];
#pragma unroll
  for (int nt = 0; nt < 4; ++nt)
#pragma unroll
    for (int ks = 0; ks < 2; ++ks) {
      int row = nhalf*64 + nt*16 + p;
      int kb = ks*32 + q*8;
      short8v f;
#pragma unroll
      for (int j = 0; j < 8; ++j) f[j] = (short)f2bf(wu[row*NM + kb + j]);
      wfu[nt][ks] = f;
    }
  if (t < NM) { float sc = bnd_stat[t*2]; s_c1[t] = sc; s_c0[t] = bd[t]*sc + bnd_stat[t*2+1]; }
  for (int i = t; i < NO; i += 256) s_bu[i] = bu[i];

  float ss[4], ss2[4];
#pragma unroll
  for (int nt = 0; nt < 4; ++nt) { ss[nt] = 0.f; ss2[nt] = 0.f; }

  for (int gi = 0; gi < TPW; ++gi) {
    int tile = blk*TPW + gi;
    int bg0 = tile*2;
    int b = bg0 >> 11, g0 = bg0 & (NG-1);
    __syncthreads();
#pragma unroll
    for (int it = 0; it < 8; ++it) {
      int i = t + it*256;
      int ch = i >> 4, p4 = (i & 15)*4;
      f32x4 x = *(const f32x4*)&out[(((size_t)b*NO + ch)*NG + g0)*NK + p4];
      int swz = ((((ch>>3) ^ ((p4>>2)&7))<<3) | (ch&7));
#pragma unroll
      for (int r = 0; r < 4; ++r) xT[(p4+r)*XS + swz] = f2bf(x[r]);
    }
    __syncthreads();
    // down -> h -> hT
    {
      f32x4 acc[4];
#pragma unroll
      for (int nt = 0; nt < 4; ++nt) acc[nt] = (f32x4){0.f,0.f,0.f,0.f};
#pragma unroll
      for (int ks = 0; ks < 4; ++ks) {
        int pos = w*16 + p;
        int kb8 = ks*4 + q;
        short8v a = *(const short8v*)&xT[pos*XS + ((kb8 ^ ((pos>>2)&7))<<3)];
#pragma unroll
        for (int nt = 0; nt < 4; ++nt) acc[nt] = MFMA(a, wfd[nt][ks], acc[nt]);
      }
#pragma unroll
      for (int nt = 0; nt < 4; ++nt) {
        int ch = nt*16 + p;
        float c1 = s_c1[ch], c0 = s_c0[ch];
#pragma unroll
        for (int r = 0; r < 4; ++r) {
          int pos = w*16 + q*4 + r;
          float hv = fmaxf(acc[nt][r]*c1 + c0, 0.f);
          hT[pos*HS + ((((ch>>3) ^ ((pos>>2)&7))<<3) | (ch&7))] = f2bf(hv);
        }
      }
    }
    __syncthreads();
    // up + stats
    {
      f32x4 acc[2][4];
#pragma unroll
      for (int mt = 0; mt < 2; ++mt)
#pragma unroll
        for (int nt = 0; nt < 4; ++nt) acc[mt][nt] = (f32x4){0.f,0.f,0.f,0.f};
#pragma unroll
      for (int ks = 0; ks < 2; ++ks) {
#pragma unroll
        for (int mt = 0; mt < 2; ++mt) {
          int pos = mpair*32 + mt*16 + p;
          int kb8 = ks*4 + q;
          short8v a = *(const short8v*)&hT[pos*HS + ((kb8 ^ ((pos>>2)&7))<<3)];
#pragma unroll
          for (int nt = 0; nt < 4; ++nt) acc[mt][nt] = MFMA(a, wfu[nt][ks], acc[mt][nt]);
        }
      }
#pragma unroll
      for (int nt = 0; nt < 4; ++nt) {
        float buv = s_bu[nhalf*64 + nt*16 + p];
#pragma unroll
        for (int mt = 0; mt < 2; ++mt)
#pragma unroll
          for (int r = 0; r < 4; ++r) { float v = acc[mt][nt][r] + buv; ss[nt] += v; ss2[nt] += v*v; }
      }
    }
  }
#pragma unroll
  for (int nt = 0; nt < 4; ++nt) {
    float v = ss[nt], v2 = ss2[nt];
    v += __shfl_xor(v, 16); v += __shfl_xor(v, 32);
    v2 += __shfl_xor(v2, 16); v2 += __shfl_xor(v2, 32);
    if (q == 0) {
      int ch = nhalf*64 + nt*16 + p;
      size_t row = (size_t)blk*2 + mpair;
      part[(row*NO + ch)*2 + 0] = v;
      part[(row*NO + ch)*2 + 1] = v2;
    }
  }
}

// ---------------- pass C: full block + residual (+ optional next down partials) ----------------
__global__ __launch_bounds__(256) void k_bfin(float* __restrict__ out,
                                              const float* __restrict__ wd,
                                              const float* __restrict__ bd,
                                              const float* __restrict__ wu,
                                              const float* __restrict__ bu,
                                              const float* __restrict__ bnd_stat,
                                              const float* __restrict__ bnu_stat,
                                              const float* __restrict__ wdn,
                                              const float* __restrict__ bdn,
                                              float* __restrict__ part,
                                              int do_next) {
  __shared__ __align__(16) unsigned short xT[64*XS];   // 17408
  __shared__ __align__(16) unsigned short hT[64*HS];   // 9216
  __shared__ __align__(16) float uB[128*68];           // 34816
  __shared__ float s_c1[NM], s_c0[NM], s_u1[NO], s_u0[NO], s_bdn[NM];
  int t = threadIdx.x, blk = blockIdx.x;
  int lane = t & 63, w = t >> 6;
  int p = lane & 15, q = lane >> 4;
  int mpair = w & 1, nhalf = w >> 1;

  short8v wfd[4][4];
#pragma unroll
  for (int nt = 0; nt < 4; ++nt)
#pragma unroll
    for (int ks = 0; ks < 4; ++ks) {
      short8v f;
#pragma unroll
      for (int j = 0; j < 8; ++j) f[j] = (short)f2bf(wd[(nt*16+p)*NO + ks*32 + q*8 + j]);
      wfd[nt][ks] = f;
    }
  short8v wfu[4][2];
#pragma unroll
  for (int nt = 0; nt < 4; ++nt)
#pragma unroll
    for (int ks = 0; ks < 2; ++ks) {
      short8v f;
#pragma unroll
      for (int j = 0; j < 8; ++j) f[j] = (short)f2bf(wu[(nhalf*64+nt*16+p)*NM + ks*32 + q*8 + j]);
      wfu[nt][ks] = f;
    }
  short8v wfn[4][4];
  if (do_next) {
#pragma unroll
    for (int nt = 0; nt < 4; ++nt)
#pragma unroll
      for (int ks = 0; ks < 4; ++ks) {
        short8v f;
#pragma unroll
        for (int j = 0; j < 8; ++j) f[j] = (short)f2bf(wdn[(nt*16+p)*NO + ks*32 + q*8 + j]);
        wfn[nt][ks] = f;
      }
  }
  if (t < NM) {
    float sc = bnd_stat[t*2];
    s_c1[t] = sc; s_c0[t] = bd[t]*sc + bnd_stat[t*2+1];
    s_bdn[t] = do_next ? bdn[t] : 0.f;
  }
  for (int i = t; i < NO; i += 256) {
    float sc = bnu_stat[i*2];
    s_u1[i] = sc; s_u0[i] = bu[i]*sc + bnu_stat[i*2+1];
  }

  float ss[4], ss2[4];
#pragma unroll
  for (int nt = 0; nt < 4; ++nt) { ss[nt] = 0.f; ss2[nt] = 0.f; }

  for (int gi = 0; gi < TPW; ++gi) {
    int tile = blk*TPW + gi;
    int bg0 = tile*2;
    int b = bg0 >> 11, g0 = bg0 & (NG-1);
    __syncthreads();
#pragma unroll
    for (int it = 0; it < 8; ++it) {
      int i = t + it*256;
      int ch = i >> 4, p4 = (i & 15)*4;
      f32x4 x = *(const f32x4*)&out[(((size_t)b*NO + ch)*NG + g0)*NK + p4];
      int swz = ((((ch>>3) ^ ((p4>>2)&7))<<3) | (ch&7));
#pragma unroll
      for (int r = 0; r < 4; ++r) xT[(p4+r)*XS + swz] = f2bf(x[r]);
    }
    __syncthreads();
    // down -> hT
    {
      f32x4 acc[4];
#pragma unroll
      for (int nt = 0; nt < 4; ++nt) acc[nt] = (f32x4){0.f,0.f,0.f,0.f};
#pragma unroll
      for (int ks = 0; ks < 4; ++ks) {
        int pos = w*16 + p;
        int kb8 = ks*4 + q;
        short8v a = *(const short8v*)&xT[pos*XS + ((kb8 ^ ((pos>>2)&7))<<3)];
#pragma unroll
        for (int nt = 0; nt < 4; ++nt) acc[nt] = MFMA(a, wfd[nt][ks], acc[nt]);
      }
#pragma unroll
      for (int nt = 0; nt < 4; ++nt) {
        int ch = nt*16 + p;
        float c1 = s_c1[ch], c0 = s_c0[ch];
#pragma unroll
        for (int r = 0; r < 4; ++r) {
          int pos = w*16 + q*4 + r;
          float hv = fmaxf(acc[nt][r]*c1 + c0, 0.f);
          hT[pos*HS + ((((ch>>3) ^ ((pos>>2)&7))<<3) | (ch&7))] = f2bf(hv);
        }
      }
    }
    __syncthreads();
    // up -> u (bn applied) -> uB
    {
      f32x4 acc[2][4];
#pragma unroll
      for (int mt = 0; mt < 2; ++mt)
#pragma unroll
        for (int nt = 0; nt < 4; ++nt) acc[mt][nt] = (f32x4){0.f,0.f,0.f,0.f};
#pragma unroll
      for (int ks = 0; ks < 2; ++ks) {
#pragma unroll
        for (int mt = 0; mt < 2; ++mt) {
          int pos = mpair*32 + mt*16 + p;
          int kb8 = ks*4 + q;
          short8v a = *(const short8v*)&hT[pos*HS + ((kb8 ^ ((pos>>2)&7))<<3)];
#pragma unroll
          for (int nt = 0; nt < 4; ++nt) acc[mt][nt] = MFMA(a, wfu[nt][ks], acc[mt][nt]);
        }
      }
#pragma unroll
      for (int mt = 0; mt < 2; ++mt)
#pragma unroll
        for (int nt = 0; nt < 4; ++nt) {
          int ch = nhalf*64 + nt*16 + p;
          float u1 = s_u1[ch], u0 = s_u0[ch];
          f32x4 u;
#pragma unroll
          for (int r = 0; r < 4; ++r) u[r] = acc[mt][nt][r]*u1 + u0;
          *(f32x4*)&uB[ch*68 + mpair*32 + mt*16 + q*4] = u;
        }
    }
    __syncthreads();
    // residual + write out + refill xT with new x
#pragma unroll
    for (int it = 0; it < 8; ++it) {
      int i = t + it*256;
      int ch = i >> 4, p4 = (i & 15)*4;
      size_t gaddr = (((size_t)b*NO + ch)*NG + g0)*NK + p4;
      f32x4 u = *(const f32x4*)&uB[ch*68 + p4];
      f32x4 x = *(const f32x4*)&out[gaddr];
      int swz = ((((ch>>3) ^ ((p4>>2)&7))<<3) | (ch&7));
      f32x4 xn;
#pragma unroll
      for (int r = 0; r < 4; ++r) {
        float v = fmaxf(u[r] + x[r], 0.f);
        xn[r] = v;
        if (do_next) xT[(p4+r)*XS + swz] = f2bf(v);
      }
      *(f32x4*)&out[gaddr] = xn;
    }
    if (do_next) {
      __syncthreads();
      f32x4 acc[4];
#pragma unroll
      for (int nt = 0; nt < 4; ++nt) acc[nt] = (f32x4){0.f,0.f,0.f,0.f};
#pragma unroll
      for (int ks = 0; ks < 4; ++ks) {
        int pos = w*16 + p;
        int kb8 = ks*4 + q;
        short8v a = *(const short8v*)&xT[pos*XS + ((kb8 ^ ((pos>>2)&7))<<3)];
#pragma unroll
        for (int nt = 0; nt < 4; ++nt) acc[nt] = MFMA(a, wfn[nt][ks], acc[nt]);
      }
#pragma unroll
      for (int nt = 0; nt < 4; ++nt) {
        float bdv = s_bdn[nt*16 + p];
#pragma unroll
        for (int r = 0; r < 4; ++r) { float v = acc[nt][r] + bdv; ss[nt] += v; ss2[nt] += v*v; }
      }
    }
  }
  if (do_next) {
#pragma unroll
    for (int nt = 0; nt < 4; ++nt) {
      float v = ss[nt], v2 = ss2[nt];
      v += __shfl_xor(v, 16); v += __shfl_xor(v, 32);
      v2 += __shfl_xor(v2, 16); v2 += __shfl_xor(v2, 32);
      if (q == 0) {
        int ch = nt*16 + p;
        size_t row = (size_t)blk*4 + w;
        part[(row*NM + ch)*2 + 0] = v;
        part[(row*NM + ch)*2 + 1] = v2;
      }
    }
  }
}

extern "C" void kernel_launch(void* const* d_in, const int* in_sizes, int n_in,
                              void* d_out, int out_size, void* d_ws, size_t ws_size,
                              hipStream_t stream) {
  const float* lc_xyz   = (const float*)d_in[0];
  const float* lc_feat  = (const float*)d_in[1];
  const float* knn_xyz  = (const float*)d_in[2];
  const float* knn_feat = (const float*)d_in[3];
  const float* w1       = (const float*)d_in[4];
  const float* bn1_g    = (const float*)d_in[5];
  const float* bn1_b    = (const float*)d_in[6];
  const float* wd       = (const float*)d_in[7];
  const float* bd       = (const float*)d_in[8];
  const float* dn_g     = (const float*)d_in[9];
  const float* dn_b     = (const float*)d_in[10];
  const float* wu       = (const float*)d_in[11];
  const float* bu       = (const float*)d_in[12];
  const float* up_g     = (const float*)d_in[13];
  const float* up_b     = (const float*)d_in[14];
  float* out = (float*)d_out;
  float* ws  = (float*)d_ws;

  k_std_part<<<256, 256, 0, stream>>>(knn_xyz, lc_xyz, ws + OFF_STD_PART);
  k_std_fin<<<1, 256, 0, stream>>>(ws + OFF_STD_PART, ws + OFF_STD);

  k_z1<<<NWGT, 256, 0, stream>>>(knn_feat, lc_feat, w1, out, ws + OFF_PART);
  k_fin_bn<<<128, 256, 0, stream>>>(ws + OFF_PART, 128, NROWS2, bn1_g, bn1_b, ws + OFF_STATA);

  k_x1<<<NWGT, 256, 0, stream>>>(knn_xyz, lc_xyz, wd, bd, out, ws + OFF_STD,
                                 ws + OFF_STATA, ws + OFF_PART);
  k_fin_bn<<<64, 256, 0, stream>>>(ws + OFF_PART, 64, NROWS4, dn_g, dn_b, ws + OFF_STATB);

  k_bstat<<<NWGT, 256, 0, stream>>>(out, wd, bd, wu, bu, ws + OFF_STATB, ws + OFF_PART);
  k_fin_bn<<<128, 256, 0, stream>>>(ws + OFF_PART, 128, NROWS2, up_g, up_b, ws + OFF_STATC);

  k_bfin<<<NWGT, 256, 0, stream>>>(out, wd, bd, wu, bu, ws + OFF_STATB, ws + OFF_STATC,
                                   wd + 64*128, bd + 64, ws + OFF_PART, 1);
  k_fin_bn<<<64, 256, 0, stream>>>(ws + OFF_PART, 64, NROWS4, dn_g + 64, dn_b + 64, ws + OFF_STATB);

  k_bstat<<<NWGT, 256, 0, stream>>>(out, wd + 64*128, bd + 64, wu + 128*64, bu + 128,
                                    ws + OFF_STATB, ws + OFF_PART);
  k_fin_bn<<<128, 256, 0, stream>>>(ws + OFF_PART, 128, NROWS2, up_g + 128, up_b + 128, ws + OFF_STATC);

  k_bfin<<<NWGT, 256, 0, stream>>>(out, wd + 64*128, bd + 64, wu + 128*64, bu + 128,
                                   ws + OFF_STATB, ws + OFF_STATC,
                                   (const float*)nullptr, (const float*)nullptr,
                                   ws + OFF_PART, 0);
}

// Round 4
// 801.297 us; speedup vs baseline: 3.9765x; 1.6822x over previous
//
#include <hip/hip_runtime.h>
#include <math.h>

#define NB 8
#define NG 2048
#define NK 32
#define NO 128
#define NM 64
#define NC 131
#define NPT (NB*NG*NK)      // 524288 positions
#define NWGT 2048           // blocks for tile passes
#define TPW 4               // tiles (of 64 positions) per workgroup

// LDS row strides (bf16 elements); octet count multiple of 8 so the
// (c>>3)^((pos>>2)&7) swizzle is closed within each row.
#define XS 136              // xT (K=128 -> 16 octets + pad)
#define ES 192              // eT (K padded 131->160 -> 24 octets)
#define HS 72               // hT (K=64 -> 8 octets + pad)
#define ZS 76               // zb16 stride (plain, no swizzle)

// workspace layout (float offsets)
#define OFF_STD_PART 0
#define OFF_STD      512
#define OFF_STATA    1024   // 256
#define OFF_STATB    1536   // 128
#define OFF_STATC    2048   // 256
#define OFF_PART     4096   // <= 2048*128*2 floats

typedef __attribute__((ext_vector_type(8))) short short8v;
typedef __attribute__((ext_vector_type(4))) float f32x4;
typedef __attribute__((ext_vector_type(4))) unsigned short u16x4;

#define MFMA(a,b,c) __builtin_amdgcn_mfma_f32_16x16x32_bf16(a,b,c,0,0,0)

__device__ inline unsigned short f2bf(float f) {
  unsigned u = __builtin_bit_cast(unsigned, f);
  unsigned r = u + 0x7fffu + ((u >> 16) & 1u);
  return (unsigned short)(r >> 16);
}
__device__ inline float bf2f(unsigned short h) {
  unsigned u = ((unsigned)h) << 16;
  return __builtin_bit_cast(float, u);
}
__device__ inline int swzo(int ch, int pos) {   // swizzled within-row element offset
  return (((ch >> 3) ^ ((pos >> 2) & 7)) << 3) | (ch & 7);
}

// ---------------- std of rel0 (ddof=1) ----------------
__global__ __launch_bounds__(256) void k_std_part(const float* __restrict__ knn_xyz,
                                                  const float* __restrict__ lc_xyz,
                                                  float* __restrict__ part) {
  int t = threadIdx.x, blk = blockIdx.x;
  int gsz = gridDim.x * blockDim.x;
  float s = 0.f, s2 = 0.f;
  for (int i = blk*256 + t; i < NPT*3; i += gsz) {
    int d = i % 3;
    int pk = i / 3;
    int bg = pk / NK;
    float r = knn_xyz[i] - lc_xyz[bg*3 + d];
    s += r; s2 += r*r;
  }
  __shared__ float ls[256], ls2[256];
  ls[t] = s; ls2[t] = s2; __syncthreads();
  for (int off = 128; off >= 1; off >>= 1) {
    if (t < off) { ls[t] += ls[t+off]; ls2[t] += ls2[t+off]; }
    __syncthreads();
  }
  if (t == 0) { part[blk*2] = ls[0]; part[blk*2+1] = ls2[0]; }
}

__global__ __launch_bounds__(256) void k_std_fin(const float* __restrict__ part,
                                                 float* __restrict__ wsc) {
  int t = threadIdx.x;
  __shared__ float ls[256], ls2[256];
  ls[t] = part[t*2]; ls2[t] = part[t*2+1]; __syncthreads();
  for (int off = 128; off >= 1; off >>= 1) {
    if (t < off) { ls[t] += ls[t+off]; ls2[t] += ls2[t+off]; }
    __syncthreads();
  }
  if (t == 0) {
    double S = ls[0], S2 = ls2[0];
    double n = (double)NPT * 3.0;
    double var = (S2 - S*S/n) / (n - 1.0);
    wsc[0] = (float)(sqrt(var) + 1e-5);
  }
}

// ---------------- BN finalize ----------------
__global__ __launch_bounds__(256) void k_fin_bn(const float* __restrict__ part, int C, int nrows,
                                                const float* __restrict__ gamma,
                                                const float* __restrict__ beta,
                                                float* __restrict__ stat) {
  int o = blockIdx.x, t = threadIdx.x;
  float s = 0.f, s2 = 0.f;
  for (int r = t; r < nrows; r += 256) {
    s  += part[((size_t)r*C + o)*2 + 0];
    s2 += part[((size_t)r*C + o)*2 + 1];
  }
  __shared__ float ls[256], ls2[256];
  ls[t] = s; ls2[t] = s2; __syncthreads();
  for (int off = 128; off >= 1; off >>= 1) {
    if (t < off) { ls[t] += ls[t+off]; ls2[t] += ls2[t+off]; }
    __syncthreads();
  }
  if (t == 0) {
    float n = (float)NPT;
    float mean = ls[0] / n;
    float var  = ls2[0] / n - mean*mean;
    float sc = gamma[o] * rsqrtf(var + 1e-5f);
    stat[o*2]   = sc;
    stat[o*2+1] = beta[o] - mean*sc;
  }
}

// ---------------- z1 = expanded @ W1^T, write (bf16-rounded) f32, BN1 partials ----------------
// waves split N: wave w owns out-channels [w*32, w*32+32)
__global__ __launch_bounds__(256,3) void k_z1(const float* __restrict__ knn_feat,
                                              const float* __restrict__ lc_feat,
                                              const float* __restrict__ w1,
                                              float* __restrict__ out,
                                              float* __restrict__ part) {
  __shared__ __align__(16) unsigned short eT[64*ES];     // 24576 B
  __shared__ __align__(16) unsigned short zb16[128*ZS];  // 19456 B
  int t = threadIdx.x, blk = blockIdx.x;
  int lane = t & 63, w = t >> 6;
  int p = lane & 15, q = lane >> 4;

  short8v wf[2][5];
#pragma unroll
  for (int ntl = 0; ntl < 2; ++ntl)
#pragma unroll
    for (int ks = 0; ks < 5; ++ks) {
      int row = w*32 + ntl*16 + p;
      int kb = ks*32 + q*8;
      short8v f;
#pragma unroll
      for (int j = 0; j < 8; ++j) {
        int k = kb + j;
        f[j] = (short)((k < NC) ? f2bf(w1[row*NC + k]) : 0);
      }
      wf[ntl][ks] = f;
    }

  float ss[2] = {0.f, 0.f}, ss2[2] = {0.f, 0.f};

  for (int gi = 0; gi < TPW; ++gi) {
    int bg0 = (blk*TPW + gi)*2;
    int b = bg0 >> 11, g0 = bg0 & (NG-1);
    __syncthreads();
    const float* kf = knn_feat + (size_t)bg0*NK*67;
    for (int i = t; i < 64*67; i += 256) {
      int pos = i/67, c = i - pos*67;
      eT[pos*ES + swzo(c, pos)] = f2bf(kf[i]);
    }
    const float* lf = lc_feat + (size_t)bg0*64;
    for (int i = t; i < 64*64; i += 256) {
      int pos = i >> 6, c = i & 63;
      eT[pos*ES + swzo(67 + c, pos)] = f2bf(lf[(pos>>5)*64 + c]);
    }
    for (int i = t; i < 64*32; i += 256) {
      int pos = i >> 5, c = 131 + (i & 31);
      if (c < 160) eT[pos*ES + swzo(c, pos)] = 0;
    }
    __syncthreads();

    f32x4 acc[4][2];
#pragma unroll
    for (int mt = 0; mt < 4; ++mt)
#pragma unroll
      for (int ntl = 0; ntl < 2; ++ntl) acc[mt][ntl] = (f32x4){0.f,0.f,0.f,0.f};
#pragma unroll
    for (int ks = 0; ks < 5; ++ks)
#pragma unroll
      for (int mt = 0; mt < 4; ++mt) {
        int pos = mt*16 + p;
        short8v a = *(const short8v*)&eT[pos*ES + (((ks*4+q) ^ ((pos>>2)&7))<<3)];
#pragma unroll
        for (int ntl = 0; ntl < 2; ++ntl) acc[mt][ntl] = MFMA(a, wf[ntl][ks], acc[mt][ntl]);
      }
#pragma unroll
    for (int ntl = 0; ntl < 2; ++ntl) {
      int ch = w*32 + ntl*16 + p;
#pragma unroll
      for (int mt = 0; mt < 4; ++mt)
#pragma unroll
        for (int r = 0; r < 4; ++r) {
          float v = acc[mt][ntl][r];
          ss[ntl] += v; ss2[ntl] += v*v;
          zb16[ch*ZS + mt*16 + q*4 + r] = f2bf(v);
        }
    }
    __syncthreads();
    for (int i = t; i < 128*16; i += 256) {
      int ch = i >> 4, p4 = (i & 15)*4;
      u16x4 zv = *(const u16x4*)&zb16[ch*ZS + p4];
      f32x4 o;
#pragma unroll
      for (int r = 0; r < 4; ++r) o[r] = bf2f(zv[r]);
      *(f32x4*)&out[(((size_t)b*NO + ch)*NG + g0)*NK + p4] = o;
    }
  }
#pragma unroll
  for (int ntl = 0; ntl < 2; ++ntl) {
    float v = ss[ntl], v2 = ss2[ntl];
    v += __shfl_xor(v, 16); v += __shfl_xor(v, 32);
    v2 += __shfl_xor(v2, 16); v2 += __shfl_xor(v2, 32);
    if (q == 0) {
      int ch = w*32 + ntl*16 + p;
      part[((size_t)blk*NO + ch)*2 + 0] = v;
      part[((size_t)blk*NO + ch)*2 + 1] = v2;
    }
  }
}

// ---------------- x1 = relu(bn1(z1))*wgt (bf16-rounded, in place) + down0 partials ----------------
// down split: wave w owns h-channels [w*16, w*16+16)
__global__ __launch_bounds__(256,4) void k_x1(const float* __restrict__ knn_xyz,
                                              const float* __restrict__ lc_xyz,
                                              const float* __restrict__ wd,
                                              const float* __restrict__ bd,
                                              float* __restrict__ out,
                                              const float* __restrict__ wsc,
                                              const float* __restrict__ bn1_stat,
                                              float* __restrict__ part) {
  __shared__ __align__(16) unsigned short xT[64*XS];
  __shared__ float s_sc[NO], s_sh[NO], s_wgt[64];
  int t = threadIdx.x, blk = blockIdx.x;
  int lane = t & 63, w = t >> 6;
  int p = lane & 15, q = lane >> 4;

  short8v wfd[4];
#pragma unroll
  for (int ks = 0; ks < 4; ++ks) {
    short8v f;
#pragma unroll
    for (int j = 0; j < 8; ++j) f[j] = (short)f2bf(wd[(w*16+p)*NO + ks*32 + q*8 + j]);
    wfd[ks] = f;
  }
  for (int i = t; i < NO; i += 256) { s_sc[i] = bn1_stat[i*2]; s_sh[i] = bn1_stat[i*2+1]; }
  float bdv = bd[w*16 + p];
  float inv_std = 1.0f / wsc[0];

  float ss = 0.f, ss2 = 0.f;

  for (int gi = 0; gi < TPW; ++gi) {
    int bg0 = (blk*TPW + gi)*2;
    int b = bg0 >> 11, g0 = bg0 & (NG-1);
    __syncthreads();
    if (t < 64) {
      const float* kx = knn_xyz + ((size_t)bg0*NK + t)*3;
      const float* lc = lc_xyz + ((size_t)bg0 + (t>>5))*3;
      float d2 = 0.f;
#pragma unroll
      for (int d = 0; d < 3; ++d) { float r = (kx[d]-lc[d])*inv_std - lc[d]; d2 += r*r; }
      s_wgt[t] = expf(-sqrtf(d2)*0.5f);
    }
    __syncthreads();
#pragma unroll
    for (int it = 0; it < 8; ++it) {
      int i = t + it*256;
      int ch = i >> 4, p4 = (i & 15)*4;
      size_t gaddr = (((size_t)b*NO + ch)*NG + g0)*NK + p4;
      f32x4 z = *(const f32x4*)&out[gaddr];
      float sc = s_sc[ch], sh = s_sh[ch];
      f32x4 x;
#pragma unroll
      for (int r = 0; r < 4; ++r) {
        float v = fmaxf(z[r]*sc + sh, 0.f) * s_wgt[p4+r];
        unsigned short hv = f2bf(v);
        xT[(p4+r)*XS + swzo(ch, p4+r)] = hv;
        x[r] = bf2f(hv);
      }
      *(f32x4*)&out[gaddr] = x;
    }
    __syncthreads();
    f32x4 acc[4];
#pragma unroll
    for (int mt = 0; mt < 4; ++mt) acc[mt] = (f32x4){0.f,0.f,0.f,0.f};
#pragma unroll
    for (int ks = 0; ks < 4; ++ks)
#pragma unroll
      for (int mt = 0; mt < 4; ++mt) {
        int pos = mt*16 + p;
        short8v a = *(const short8v*)&xT[pos*XS + (((ks*4+q) ^ ((pos>>2)&7))<<3)];
        acc[mt] = MFMA(a, wfd[ks], acc[mt]);
      }
#pragma unroll
    for (int mt = 0; mt < 4; ++mt)
#pragma unroll
      for (int r = 0; r < 4; ++r) { float v = acc[mt][r] + bdv; ss += v; ss2 += v*v; }
  }
  ss += __shfl_xor(ss, 16); ss += __shfl_xor(ss, 32);
  ss2 += __shfl_xor(ss2, 16); ss2 += __shfl_xor(ss2, 32);
  if (q == 0) {
    part[((size_t)blk*NM + w*16 + p)*2 + 0] = ss;
    part[((size_t)blk*NM + w*16 + p)*2 + 1] = ss2;
  }
}

// ---------------- pass B: down+up recompute, u_pre partials ----------------
__global__ __launch_bounds__(256,4) void k_bstat(const float* __restrict__ out,
                                                 const float* __restrict__ wd,
                                                 const float* __restrict__ bd,
                                                 const float* __restrict__ wu,
                                                 const float* __restrict__ bu,
                                                 const float* __restrict__ bnd_stat,
                                                 float* __restrict__ part) {
  __shared__ __align__(16) unsigned short xT[64*XS];
  __shared__ __align__(16) unsigned short hT[64*HS];
  __shared__ float s_bu[NO];
  int t = threadIdx.x, blk = blockIdx.x;
  int lane = t & 63, w = t >> 6;
  int p = lane & 15, q = lane >> 4;

  short8v wfd[4];
#pragma unroll
  for (int ks = 0; ks < 4; ++ks) {
    short8v f;
#pragma unroll
    for (int j = 0; j < 8; ++j) f[j] = (short)f2bf(wd[(w*16+p)*NO + ks*32 + q*8 + j]);
    wfd[ks] = f;
  }
  short8v wfu[2][2];
#pragma unroll
  for (int ntl = 0; ntl < 2; ++ntl)
#pragma unroll
    for (int ks = 0; ks < 2; ++ks) {
      short8v f;
#pragma unroll
      for (int j = 0; j < 8; ++j) f[j] = (short)f2bf(wu[(w*32+ntl*16+p)*NM + ks*32 + q*8 + j]);
      wfu[ntl][ks] = f;
    }
  for (int i = t; i < NO; i += 256) s_bu[i] = bu[i];
  float c1 = bnd_stat[(w*16+p)*2];
  float c0 = bd[w*16+p]*c1 + bnd_stat[(w*16+p)*2+1];

  float ss[2] = {0.f,0.f}, ss2[2] = {0.f,0.f};

  for (int gi = 0; gi < TPW; ++gi) {
    int bg0 = (blk*TPW + gi)*2;
    int b = bg0 >> 11, g0 = bg0 & (NG-1);
    __syncthreads();
#pragma unroll
    for (int it = 0; it < 8; ++it) {
      int i = t + it*256;
      int ch = i >> 4, p4 = (i & 15)*4;
      f32x4 x = *(const f32x4*)&out[(((size_t)b*NO + ch)*NG + g0)*NK + p4];
#pragma unroll
      for (int r = 0; r < 4; ++r) xT[(p4+r)*XS + swzo(ch, p4+r)] = f2bf(x[r]);
    }
    __syncthreads();
    {
      f32x4 dacc[4];
#pragma unroll
      for (int mt = 0; mt < 4; ++mt) dacc[mt] = (f32x4){0.f,0.f,0.f,0.f};
#pragma unroll
      for (int ks = 0; ks < 4; ++ks)
#pragma unroll
        for (int mt = 0; mt < 4; ++mt) {
          int pos = mt*16 + p;
          short8v a = *(const short8v*)&xT[pos*XS + (((ks*4+q) ^ ((pos>>2)&7))<<3)];
          dacc[mt] = MFMA(a, wfd[ks], dacc[mt]);
        }
      int ch = w*16 + p;
#pragma unroll
      for (int mt = 0; mt < 4; ++mt)
#pragma unroll
        for (int r = 0; r < 4; ++r) {
          int pos = mt*16 + q*4 + r;
          hT[pos*HS + swzo(ch, pos)] = f2bf(fmaxf(dacc[mt][r]*c1 + c0, 0.f));
        }
    }
    __syncthreads();
    {
      f32x4 uacc[4][2];
#pragma unroll
      for (int mt = 0; mt < 4; ++mt)
#pragma unroll
        for (int ntl = 0; ntl < 2; ++ntl) uacc[mt][ntl] = (f32x4){0.f,0.f,0.f,0.f};
#pragma unroll
      for (int ks = 0; ks < 2; ++ks)
#pragma unroll
        for (int mt = 0; mt < 4; ++mt) {
          int pos = mt*16 + p;
          short8v a = *(const short8v*)&hT[pos*HS + (((ks*4+q) ^ ((pos>>2)&7))<<3)];
#pragma unroll
          for (int ntl = 0; ntl < 2; ++ntl) uacc[mt][ntl] = MFMA(a, wfu[ntl][ks], uacc[mt][ntl]);
        }
#pragma unroll
      for (int ntl = 0; ntl < 2; ++ntl) {
        float buv = s_bu[w*32 + ntl*16 + p];
#pragma unroll
        for (int mt = 0; mt < 4; ++mt)
#pragma unroll
          for (int r = 0; r < 4; ++r) { float v = uacc[mt][ntl][r] + buv; ss[ntl] += v; ss2[ntl] += v*v; }
      }
    }
  }
#pragma unroll
  for (int ntl = 0; ntl < 2; ++ntl) {
    float v = ss[ntl], v2 = ss2[ntl];
    v += __shfl_xor(v, 16); v += __shfl_xor(v, 32);
    v2 += __shfl_xor(v2, 16); v2 += __shfl_xor(v2, 32);
    if (q == 0) {
      int ch = w*32 + ntl*16 + p;
      part[((size_t)blk*NO + ch)*2 + 0] = v;
      part[((size_t)blk*NO + ch)*2 + 1] = v2;
    }
  }
}

// ---------------- pass C: full block + residual (+ optional next down partials) ----------------
__global__ __launch_bounds__(256,4) void k_bfin(float* __restrict__ out,
                                                const float* __restrict__ wd,
                                                const float* __restrict__ bd,
                                                const float* __restrict__ wu,
                                                const float* __restrict__ bu,
                                                const float* __restrict__ bnd_stat,
                                                const float* __restrict__ bnu_stat,
                                                const float* __restrict__ wdn,
                                                const float* __restrict__ bdn,
                                                float* __restrict__ part,
                                                int do_next) {
  __shared__ __align__(16) unsigned short xT[64*XS];   // 17408 B
  __shared__ __align__(16) unsigned short hT[64*HS];   // 9216 B
  __shared__ float s_u1[NO], s_u0[NO];
  int t = threadIdx.x, blk = blockIdx.x;
  int lane = t & 63, w = t >> 6;
  int p = lane & 15, q = lane >> 4;

  short8v wfd[4];
#pragma unroll
  for (int ks = 0; ks < 4; ++ks) {
    short8v f;
#pragma unroll
    for (int j = 0; j < 8; ++j) f[j] = (short)f2bf(wd[(w*16+p)*NO + ks*32 + q*8 + j]);
    wfd[ks] = f;
  }
  short8v wfu[2][2];
#pragma unroll
  for (int ntl = 0; ntl < 2; ++ntl)
#pragma unroll
    for (int ks = 0; ks < 2; ++ks) {
      short8v f;
#pragma unroll
      for (int j = 0; j < 8; ++j) f[j] = (short)f2bf(wu[(w*32+ntl*16+p)*NM + ks*32 + q*8 + j]);
      wfu[ntl][ks] = f;
    }
  short8v wfn[4];
  if (do_next) {
#pragma unroll
    for (int ks = 0; ks < 4; ++ks) {
      short8v f;
#pragma unroll
      for (int j = 0; j < 8; ++j) f[j] = (short)f2bf(wdn[(w*16+p)*NO + ks*32 + q*8 + j]);
      wfn[ks] = f;
    }
  }
  float c1 = bnd_stat[(w*16+p)*2];
  float c0 = bd[w*16+p]*c1 + bnd_stat[(w*16+p)*2+1];
  float bdnv = do_next ? bdn[w*16+p] : 0.f;
  for (int i = t; i < NO; i += 256) {
    float sc = bnu_stat[i*2];
    s_u1[i] = sc; s_u0[i] = bu[i]*sc + bnu_stat[i*2+1];
  }

  float ss = 0.f, ss2 = 0.f;

  for (int gi = 0; gi < TPW; ++gi) {
    int bg0 = (blk*TPW + gi)*2;
    int b = bg0 >> 11, g0 = bg0 & (NG-1);
    __syncthreads();
#pragma unroll
    for (int it = 0; it < 8; ++it) {
      int i = t + it*256;
      int ch = i >> 4, p4 = (i & 15)*4;
      f32x4 x = *(const f32x4*)&out[(((size_t)b*NO + ch)*NG + g0)*NK + p4];
#pragma unroll
      for (int r = 0; r < 4; ++r) xT[(p4+r)*XS + swzo(ch, p4+r)] = f2bf(x[r]);
    }
    __syncthreads();
    // down -> hT
    {
      f32x4 dacc[4];
#pragma unroll
      for (int mt = 0; mt < 4; ++mt) dacc[mt] = (f32x4){0.f,0.f,0.f,0.f};
#pragma unroll
      for (int ks = 0; ks < 4; ++ks)
#pragma unroll
        for (int mt = 0; mt < 4; ++mt) {
          int pos = mt*16 + p;
          short8v a = *(const short8v*)&xT[pos*XS + (((ks*4+q) ^ ((pos>>2)&7))<<3)];
          dacc[mt] = MFMA(a, wfd[ks], dacc[mt]);
        }
      int ch = w*16 + p;
#pragma unroll
      for (int mt = 0; mt < 4; ++mt)
#pragma unroll
        for (int r = 0; r < 4; ++r) {
          int pos = mt*16 + q*4 + r;
          hT[pos*HS + swzo(ch, pos)] = f2bf(fmaxf(dacc[mt][r]*c1 + c0, 0.f));
        }
    }
    __syncthreads();
    // up + residual in fragment layout, write x_new back into xT
    {
      f32x4 uacc[4][2];
#pragma unroll
      for (int mt = 0; mt < 4; ++mt)
#pragma unroll
        for (int ntl = 0; ntl < 2; ++ntl) uacc[mt][ntl] = (f32x4){0.f,0.f,0.f,0.f};
#pragma unroll
      for (int ks = 0; ks < 2; ++ks)
#pragma unroll
        for (int mt = 0; mt < 4; ++mt) {
          int pos = mt*16 + p;
          short8v a = *(const short8v*)&hT[pos*HS + (((ks*4+q) ^ ((pos>>2)&7))<<3)];
#pragma unroll
          for (int ntl = 0; ntl < 2; ++ntl) uacc[mt][ntl] = MFMA(a, wfu[ntl][ks], uacc[mt][ntl]);
        }
#pragma unroll
      for (int ntl = 0; ntl < 2; ++ntl) {
        int ch = w*32 + ntl*16 + p;
        float u1 = s_u1[ch], u0 = s_u0[ch];
#pragma unroll
        for (int mt = 0; mt < 4; ++mt)
#pragma unroll
          for (int r = 0; r < 4; ++r) {
            int pos = mt*16 + q*4 + r;
            int off = pos*XS + swzo(ch, pos);
            float u = uacc[mt][ntl][r]*u1 + u0;
            float xn = fmaxf(u + bf2f(xT[off]), 0.f);
            xT[off] = f2bf(xn);
          }
      }
    }
    __syncthreads();
    // coalesced global write from xT (+ next-down MFMA reads xT)
#pragma unroll
    for (int it = 0; it < 8; ++it) {
      int i = t + it*256;
      int ch = i >> 4, p4 = (i & 15)*4;
      f32x4 o;
#pragma unroll
      for (int r = 0; r < 4; ++r) o[r] = bf2f(xT[(p4+r)*XS + swzo(ch, p4+r)]);
      *(f32x4*)&out[(((size_t)b*NO + ch)*NG + g0)*NK + p4] = o;
    }
    if (do_next) {
      f32x4 nacc[4];
#pragma unroll
      for (int mt = 0; mt < 4; ++mt) nacc[mt] = (f32x4){0.f,0.f,0.f,0.f};
#pragma unroll
      for (int ks = 0; ks < 4; ++ks)
#pragma unroll
        for (int mt = 0; mt < 4; ++mt) {
          int pos = mt*16 + p;
          short8v a = *(const short8v*)&xT[pos*XS + (((ks*4+q) ^ ((pos>>2)&7))<<3)];
          nacc[mt] = MFMA(a, wfn[ks], nacc[mt]);
        }
#pragma unroll
      for (int mt = 0; mt < 4; ++mt)
#pragma unroll
        for (int r = 0; r < 4; ++r) { float v = nacc[mt][r] + bdnv; ss += v; ss2 += v*v; }
    }
  }
  if (do_next) {
    ss += __shfl_xor(ss, 16); ss += __shfl_xor(ss, 32);
    ss2 += __shfl_xor(ss2, 16); ss2 += __shfl_xor(ss2, 32);
    if (q == 0) {
      part[((size_t)blk*NM + w*16 + p)*2 + 0] = ss;
      part[((size_t)blk*NM + w*16 + p)*2 + 1] = ss2;
    }
  }
}

extern "C" void kernel_launch(void* const* d_in, const int* in_sizes, int n_in,
                              void* d_out, int out_size, void* d_ws, size_t ws_size,
                              hipStream_t stream) {
  const float* lc_xyz   = (const float*)d_in[0];
  const float* lc_feat  = (const float*)d_in[1];
  const float* knn_xyz  = (const float*)d_in[2];
  const float* knn_feat = (const float*)d_in[3];
  const float* w1       = (const float*)d_in[4];
  const float* bn1_g    = (const float*)d_in[5];
  const float* bn1_b    = (const float*)d_in[6];
  const float* wd       = (const float*)d_in[7];
  const float* bd       = (const float*)d_in[8];
  const float* dn_g     = (const float*)d_in[9];
  const float* dn_b     = (const float*)d_in[10];
  const float* wu       = (const float*)d_in[11];
  const float* bu       = (const float*)d_in[12];
  const float* up_g     = (const float*)d_in[13];
  const float* up_b     = (const float*)d_in[14];
  float* out = (float*)d_out;
  float* ws  = (float*)d_ws;

  k_std_part<<<256, 256, 0, stream>>>(knn_xyz, lc_xyz, ws + OFF_STD_PART);
  k_std_fin<<<1, 256, 0, stream>>>(ws + OFF_STD_PART, ws + OFF_STD);

  k_z1<<<NWGT, 256, 0, stream>>>(knn_feat, lc_feat, w1, out, ws + OFF_PART);
  k_fin_bn<<<128, 256, 0, stream>>>(ws + OFF_PART, 128, NWGT, bn1_g, bn1_b, ws + OFF_STATA);

  k_x1<<<NWGT, 256, 0, stream>>>(knn_xyz, lc_xyz, wd, bd, out, ws + OFF_STD,
                                 ws + OFF_STATA, ws + OFF_PART);
  k_fin_bn<<<64, 256, 0, stream>>>(ws + OFF_PART, 64, NWGT, dn_g, dn_b, ws + OFF_STATB);

  k_bstat<<<NWGT, 256, 0, stream>>>(out, wd, bd, wu, bu, ws + OFF_STATB, ws + OFF_PART);
  k_fin_bn<<<128, 256, 0, stream>>>(ws + OFF_PART, 128, NWGT, up_g, up_b, ws + OFF_STATC);

  k_bfin<<<NWGT, 256, 0, stream>>>(out, wd, bd, wu, bu, ws + OFF_STATB, ws + OFF_STATC,
                                   wd + 64*128, bd + 64, ws + OFF_PART, 1);
  k_fin_bn<<<64, 256, 0, stream>>>(ws + OFF_PART, 64, NWGT, dn_g + 64, dn_b + 64, ws + OFF_STATB);

  k_bstat<<<NWGT, 256, 0, stream>>>(out, wd + 64*128, bd + 64, wu + 128*64, bu + 128,
                                    ws + OFF_STATB, ws + OFF_PART);
  k_fin_bn<<<128, 256, 0, stream>>>(ws + OFF_PART, 128, NWGT, up_g + 128, up_b + 128, ws + OFF_STATC);

  k_bfin<<<NWGT, 256, 0, stream>>>(out, wd + 64*128, bd + 64, wu + 128*64, bu + 128,
                                   ws + OFF_STATB, ws + OFF_STATC,
                                   (const float*)nullptr, (const float*)nullptr,
                                   ws + OFF_PART, 0);
}